// Round 5
// baseline (169.453 us; speedup 1.0000x reference)
//
#include <hip/hip_runtime.h>

typedef __bf16 bf16_t;
typedef __bf16 bf16x8 __attribute__((ext_vector_type(8)));
typedef float f32x4 __attribute__((ext_vector_type(4)));

#define MFMA_BF16(a, b, c) __builtin_amdgcn_mfma_f32_16x16x32_bf16((a), (b), (c), 0, 0, 0)

static constexpr int Bn = 4096;
static constexpr int Dn = 1024;
static constexpr int Rn = 256;
static constexpr int BT = 16;
static constexpr float DTv = 0.01f;
static constexpr float HDT = 0.005f;

// XOR-swizzle within a 1024-float row: flips bits [4:2] by bits [7:5]. Bijective,
// preserves 4-float (16B) contiguity, spreads stride-16-float access over bank-slots.
__device__ __forceinline__ int swz(int col) { return col ^ (((col >> 5) & 7) << 2); }

// ---- Fused setup (one launch, 56 blocks x 1024):
// blocks 0..31: pack U (kb=b)    — coalesced row-tile load -> LDS -> fragment writes
// blocks 32..39: pack W (kb=b-32) — coalesced row-tile load -> LDS -> fragment writes
// blocks 40..55: WU = W@U (m=b-40), raw-U B-ring (4 full lines/instr, L2/L3-cached)
// Upk[((ct*32+kb)*64+l)*8+j] = U[kb*32+(l>>4)*8+j][ct*16+(l&15)]
// Wpk[((ct*8+kb)*64+l)*8+j]  = W[kb*32+(l>>4)*8+j][ct*16+(l&15)]
// WUpk same layout as Wpk for WU[256x256].
__global__ __launch_bounds__(1024)
void setup_kernel(const float* __restrict__ U, const float* __restrict__ W,
                  bf16_t* __restrict__ Upk, bf16_t* __restrict__ Wpk,
                  bf16_t* __restrict__ WUpk) {
  __shared__ __align__(16) char ssm[66816];
  const int tid = (int)threadIdx.x;
  const int b = (int)blockIdx.x;
  const int l = tid & 63;
  const int wv = tid >> 6;
  const int ln = l & 15;
  const int quad = l >> 4;

  if (b < 32) {  // ---- pack U, kb = b: tile U[32 rows][256 cols] ----
    bf16_t* ubuf = (bf16_t*)ssm;  // [32][268]
    const int row = tid >> 5, c0 = (tid & 31) * 8;
    const float* src = U + (size_t)(b * 32 + row) * Rn + c0;
    f32x4 u0 = *(const f32x4*)src;
    f32x4 u1 = *(const f32x4*)(src + 4);
    bf16_t* d = ubuf + row * 268 + c0;
#pragma unroll
    for (int j = 0; j < 4; ++j) { d[j] = (bf16_t)u0[j]; d[4 + j] = (bf16_t)u1[j]; }
    __syncthreads();
    bf16x8 v;  // wave wv emits ct = wv
#pragma unroll
    for (int j = 0; j < 8; ++j) v[j] = ubuf[(quad * 8 + j) * 268 + wv * 16 + ln];
    ((bf16x8*)Upk)[(size_t)(wv * 32 + b) * 64 + l] = v;
  } else if (b < 40) {  // ---- pack W, kb = b-32: tile W[32 rows][1024 cols] ----
    const int kb = b - 32;
    bf16_t* wbuf2 = (bf16_t*)ssm;  // [32][1044]
    const int row = tid >> 5, c0 = (tid & 31) * 32;
    const float* src = W + (size_t)(kb * 32 + row) * Dn + c0;
    bf16_t* d = wbuf2 + row * 1044 + c0;
#pragma unroll
    for (int k = 0; k < 8; ++k) {
      f32x4 u = *(const f32x4*)(src + k * 4);
#pragma unroll
      for (int j = 0; j < 4; ++j) d[k * 4 + j] = (bf16_t)u[j];
    }
    __syncthreads();
#pragma unroll
    for (int cc = 0; cc < 4; ++cc) {  // wave wv emits cts {wv, wv+16, wv+32, wv+48}
      const int ct = wv + cc * 16;
      bf16x8 v;
#pragma unroll
      for (int j = 0; j < 8; ++j) v[j] = wbuf2[(quad * 8 + j) * 1044 + ct * 16 + ln];
      ((bf16x8*)Wpk)[(size_t)(ct * 8 + kb) * 64 + l] = v;
    }
  } else {  // ---- WU = W @ U, block m owns W rows m*16..+16 ----
    const int m = b - 40;
    bf16_t* wbuf = (bf16_t*)ssm;  // [16][1032]
    {
      int row = tid >> 6;
      int c0 = (tid & 63) * 16;
      const float* src = W + (size_t)(m * 16 + row) * Dn + c0;
      bf16_t* dst = wbuf + row * 1032 + c0;
#pragma unroll
      for (int j = 0; j < 16; ++j) dst[j] = (bf16_t)src[j];
    }
    __syncthreads();
    const int ucol = wv * 16 + ln;
    float uf[8][8];  // depth-8 ring, fully unrolled
#pragma unroll
    for (int p = 0; p < 8; ++p)
#pragma unroll
      for (int j = 0; j < 8; ++j)
        uf[p][j] = U[(size_t)(p * 32 + quad * 8 + j) * Rn + ucol];
    f32x4 acc = {0.f, 0.f, 0.f, 0.f};
    const bf16_t* arow = wbuf + ln * 1032 + quad * 8;
#pragma unroll
    for (int kb = 0; kb < 32; ++kb) {
      bf16x8 bb;
#pragma unroll
      for (int j = 0; j < 8; ++j) bb[j] = (bf16_t)uf[kb & 7][j];
      const bf16x8 a = *(const bf16x8*)(arow + kb * 32);
      acc = MFMA_BF16(a, bb, acc);
      if (kb < 24) {
#pragma unroll
        for (int j = 0; j < 8; ++j)
          uf[kb & 7][j] = U[(size_t)((kb + 8) * 32 + quad * 8 + j) * Rn + ucol];
      }
    }
#pragma unroll
    for (int r = 0; r < 4; ++r) {  // scatter to packed slots
      int rw = m * 16 + quad * 4 + r;
      int kb = rw >> 5;
      int sub = (rw >> 3) & 3;
      int j = rw & 7;
      size_t slot = ((size_t)(wv * 8 + kb) * 64 + sub * 16 + ln) * 8 + j;
      WUpk[slot] = (bf16_t)acc[r];
    }
  }
}

// ---- Fused integrator, R-space loop; 8 waves (512 thr), wave owns 2 R-ct tiles ----
//   hv_{h+1} = hv_h + hdt*(FU - T_h@WU),  FU = f@U, WU = W@U
//   v_out = v0 + s*dt*f - hdt*(S1@W),     S1 = sum T_h
//   x_out = x0 + s*dt*v0 + s^2*dt*hdt*f - dt*hdt*(S2@W),  S2 = sum c_h*T_h, c_h = s-ceil(h/2)
// Loop LDS traffic = 8 waves x 8KB T-tile (halved vs 16 waves); A-frags read once/iter
// shared by both ct chains. 2 waves/EU -> 256-VGPR budget.
__global__ __launch_bounds__(512)
__attribute__((amdgpu_waves_per_eu(2, 2)))
void integrate_kernel(const float* __restrict__ x_in, const float* __restrict__ v_in,
                      const float* __restrict__ force,
                      const bf16_t* __restrict__ Upk, const bf16_t* __restrict__ Wpk,
                      const bf16_t* __restrict__ WUpk,
                      const int* __restrict__ steps_p, float* __restrict__ out) {
  // union: init abuf[3][16][1032] bf16 (99072 B) / loop tbf[2][16][264] bf16
  //        / final sbuf[2][16][264] bf16 / epilogue fsb[8][1024] f32 (32 KB)
  __shared__ __align__(16) char smem[99072];
  bf16_t* abuf = (bf16_t*)smem;
  float* fsb = (float*)smem;

  const int tid = (int)threadIdx.x;
  const int wv = tid >> 6;  // 0..7
  const int l = tid & 63;
  const int ln = l & 15;
  const int quad = l >> 4;
  const int s = steps_p[0];
  const int nhalf = 2 * s;
  const int row_base = (int)blockIdx.x * BT;

  float* out_x = out;
  float* out_v = out + (size_t)Bn * Dn;

  float xs[8][4], vs[8][4];  // ORIGINAL x0, v0 (C/D layout, 8 col-tiles/wave)
  bf16_t fsv[8][4];

  // ---- direct C/D loads: 16 lanes x 64B contiguous per instr => line-perfect ----
#pragma unroll
  for (int i = 0; i < 8; ++i) {
    const int col = (wv * 8 + i) * 16 + ln;
#pragma unroll
    for (int r = 0; r < 4; ++r) {
      const size_t g = (size_t)(row_base + quad * 4 + r) * Dn + col;
      xs[i][r] = x_in[g];
      vs[i][r] = v_in[g];
      fsv[i][r] = (bf16_t)force[g];
    }
  }
  // ---- stage full-width abuf directly from regs ----
#pragma unroll
  for (int i = 0; i < 8; ++i) {
    const int col = (wv * 8 + i) * 16 + ln;
#pragma unroll
    for (int r = 0; r < 4; ++r) {
      const int ro = (quad * 4 + r) * 1032 + col;
      abuf[ro] = (bf16_t)xs[i][r];
      abuf[16512 + ro] = (bf16_t)vs[i][r];
      abuf[33024 + ro] = fsv[i][r];
    }
  }
  __syncthreads();

  // ---- init: hx0/hv0/FU for cts {2wv, 2wv+1}; ONE 64-fragment Upk pass ----
  f32x4 hx[2], hv[2], FU[2];
#pragma unroll
  for (int c = 0; c < 2; ++c) {
    hx[c] = (f32x4){0.f, 0.f, 0.f, 0.f};
    hv[c] = (f32x4){0.f, 0.f, 0.f, 0.f};
    FU[c] = (f32x4){0.f, 0.f, 0.f, 0.f};
  }
  {
    const bf16x8* up = (const bf16x8*)Upk + (size_t)(wv * 64) * 64 + l;
    const bf16_t* ax = abuf + ln * 1032 + quad * 8;
    bf16x8 ur[8];
#pragma unroll
    for (int p = 0; p < 8; ++p) ur[p] = up[p * 64];
#pragma unroll
    for (int f = 0; f < 64; ++f) {
      const bf16x8 bfr = ur[f & 7];
      if (f < 56) ur[f & 7] = up[(f + 8) * 64];
      const int kb = f & 31, c = f >> 5;
      const bf16x8 a0 = *(const bf16x8*)(ax + kb * 32);
      const bf16x8 a1 = *(const bf16x8*)(ax + 16512 + kb * 32);
      const bf16x8 a2 = *(const bf16x8*)(ax + 33024 + kb * 32);
      hx[c] = MFMA_BF16(a0, bfr, hx[c]);
      hv[c] = MFMA_BF16(a1, bfr, hv[c]);
      FU[c] = MFMA_BF16(a2, bfr, FU[c]);
    }
  }
  __syncthreads();  // abuf dead

  // ---- WU fragments for cts {2wv, 2wv+1}, register-resident (32 VGPRs) ----
  bf16x8 wu[2][8];
  {
    const bf16x8* wub = (const bf16x8*)WUpk + (size_t)(wv * 2) * 8 * 64 + l;
#pragma unroll
    for (int c = 0; c < 2; ++c)
#pragma unroll
      for (int kb = 0; kb < 8; ++kb) wu[c][kb] = wub[(c * 8 + kb) * 64];
  }

  // ---- R-space loop: zero global traffic; dbuf T, 1 barrier/half-step ----
  f32x4 S1[2], S2[2];
#pragma unroll
  for (int c = 0; c < 2; ++c) {
    S1[c] = (f32x4){0.f, 0.f, 0.f, 0.f};
    S2[c] = (f32x4){0.f, 0.f, 0.f, 0.f};
  }
  bf16_t* tbase = (bf16_t*)smem;
  for (int h = 0; h < nhalf; ++h) {
    if (h & 1) {
#pragma unroll
      for (int c = 0; c < 2; ++c)
#pragma unroll
        for (int r = 0; r < 4; ++r) hx[c][r] += DTv * hv[c][r];
    }
    const float ch = (float)(s - ((h + 1) >> 1));
    bf16_t* tb = tbase + (h & 1) * 4224;
#pragma unroll
    for (int c = 0; c < 2; ++c)
#pragma unroll
      for (int r = 0; r < 4; ++r) {
        float a = fminf(fmaxf(hx[c][r], -15.f), 15.f);
        const float e = __expf(2.f * a);
        const float gate = 1.f - 2.f * __builtin_amdgcn_rcpf(e + 1.f);  // tanh(a)
        const float t = gate * hv[c][r] * hv[c][r];
        S1[c][r] += t;
        S2[c][r] += ch * t;
        tb[(quad * 4 + r) * 264 + (wv * 2 + c) * 16 + ln] = (bf16_t)t;
      }
    __syncthreads();
    // A-frags read once, shared by both ct chains
    const bf16_t* trow = tb + ln * 264 + quad * 8;
    bf16x8 a[8];
#pragma unroll
    for (int kb = 0; kb < 8; ++kb) a[kb] = *(const bf16x8*)(trow + kb * 32);
    f32x4 g[2][2];
#pragma unroll
    for (int c = 0; c < 2; ++c)
#pragma unroll
      for (int p = 0; p < 2; ++p) g[c][p] = (f32x4){0.f, 0.f, 0.f, 0.f};
#pragma unroll
    for (int kb = 0; kb < 8; ++kb) {
      g[0][kb & 1] = MFMA_BF16(a[kb], wu[0][kb], g[0][kb & 1]);
      g[1][kb & 1] = MFMA_BF16(a[kb], wu[1][kb], g[1][kb & 1]);
    }
#pragma unroll
    for (int c = 0; c < 2; ++c)
#pragma unroll
      for (int r = 0; r < 4; ++r)
        hv[c][r] += HDT * (FU[c][r] - (g[c][0][r] + g[c][1][r]));
    // no second barrier: next iteration writes the OTHER buffer
  }
  __syncthreads();  // all T reads done before sbuf overwrite

  // ---- final: G1 = S1@W, G2 = S2@W; wave owns 8 D-ct tiles; depth-2 rings ----
  bf16_t* sbuf = (bf16_t*)smem;
#pragma unroll
  for (int c = 0; c < 2; ++c)
#pragma unroll
    for (int r = 0; r < 4; ++r) {
      const int ro = (quad * 4 + r) * 264 + (wv * 2 + c) * 16 + ln;
      sbuf[ro] = (bf16_t)S1[c][r];
      sbuf[4224 + ro] = (bf16_t)S2[c][r];
    }
  __syncthreads();
  f32x4 ac1[8], ac2[8];
#pragma unroll
  for (int i = 0; i < 8; ++i) {
    ac1[i] = (f32x4){0.f, 0.f, 0.f, 0.f};
    ac2[i] = (f32x4){0.f, 0.f, 0.f, 0.f};
  }
  {
    const bf16x8* wp = (const bf16x8*)Wpk + (size_t)(wv * 8) * 8 * 64 + l;
    const bf16_t* s1row = sbuf + ln * 264 + quad * 8;
    const bf16_t* s2row = s1row + 4224;
    bf16x8 wr[8][2];
#pragma unroll
    for (int i = 0; i < 8; ++i) {
      wr[i][0] = wp[i * 512];
      wr[i][1] = wp[i * 512 + 64];
    }
#pragma unroll
    for (int kb = 0; kb < 8; ++kb) {
      const bf16x8 a1 = *(const bf16x8*)(s1row + kb * 32);
      const bf16x8 a2 = *(const bf16x8*)(s2row + kb * 32);
#pragma unroll
      for (int i = 0; i < 8; ++i) {
        const bf16x8 bfr = wr[i][kb & 1];
        if (kb < 6) wr[i][kb & 1] = wp[i * 512 + (kb + 2) * 64];
        ac1[i] = MFMA_BF16(a1, bfr, ac1[i]);
        ac2[i] = MFMA_BF16(a2, bfr, ac2[i]);
      }
    }
  }
  __syncthreads();  // sbuf reads done before fsb overwrite

  // ---- epilogue: closed form, lane-contiguous full-line stores via swizzled LDS ----
  const float sf = (float)s;
  const float c_vf = sf * DTv;
  const float c_xf = sf * sf * DTv * HDT;
  int csw[8];
#pragma unroll
  for (int i = 0; i < 8; ++i) csw[i] = swz((wv * 8 + i) * 16 + ln);
  auto store_chunk = [&](float* __restrict__ dstA, int HF, auto vex) {
    if ((quad >> 1) == HF) {
#pragma unroll
      for (int i = 0; i < 8; ++i)
#pragma unroll
        for (int r = 0; r < 4; ++r)
          fsb[((quad & 1) * 4 + r) * 1024 + csw[i]] = vex(i, r);
    }
    __syncthreads();
    float* dst_ = dstA + (size_t)(row_base + HF * 8) * Dn;
#pragma unroll
    for (int k = 0; k < 4; ++k) {
      const int fi = k * 2048 + tid * 4;
      *(f32x4*)(dst_ + fi) = *(const f32x4*)(fsb + (fi >> 10) * 1024 + swz(fi & 1023));
    }
    __syncthreads();
  };
  auto vval = [&](int i, int r) {
    return vs[i][r] + c_vf * (float)fsv[i][r] - HDT * ac1[i][r];
  };
  auto xval = [&](int i, int r) {
    return xs[i][r] + c_vf * vs[i][r] + c_xf * (float)fsv[i][r] - DTv * HDT * ac2[i][r];
  };
  store_chunk(out_v, 0, vval);
  store_chunk(out_v, 1, vval);
  store_chunk(out_x, 0, xval);
  store_chunk(out_x, 1, xval);
}

extern "C" void kernel_launch(void* const* d_in, const int* in_sizes, int n_in,
                              void* d_out, int out_size, void* d_ws, size_t ws_size,
                              hipStream_t stream) {
  const float* x = (const float*)d_in[0];
  const float* v = (const float*)d_in[1];
  const float* force = (const float*)d_in[2];
  const float* U = (const float*)d_in[3];
  const float* W = (const float*)d_in[4];
  const int* steps = (const int*)d_in[5];

  bf16_t* Upk = (bf16_t*)d_ws;                          // 512 KB
  bf16_t* Wpk = (bf16_t*)((char*)d_ws + 512 * 1024);    // 512 KB
  bf16_t* WUpk = (bf16_t*)((char*)d_ws + 1024 * 1024);  // 128 KB

  setup_kernel<<<56, 1024, 0, stream>>>(U, W, Upk, Wpk, WUpk);
  integrate_kernel<<<Bn / BT, 512, 0, stream>>>(x, v, force, Upk, Wpk, WUpk, steps,
                                                (float*)d_out);
}